// Round 17
// baseline (1731.678 us; speedup 1.0000x reference)
//
#include <hip/hip_runtime.h>
#include <stdint.h>
#include <math.h>

// Problem constants (B, H, T) = (16, 2048, 512)
#define Hdim   2048
#define Bdim   16
#define Tsteps 512
#define NWG    128   // workgroups; each owns KC columns of h (R6-proven optimum)
#define TPB    256   // 4 waves
#define KC     16    // h-columns per WG  (NWG*KC == Hdim)
#define NCHUNK 16    // K-chunks of 32 per wave (wave K-range = 512)
#define FLAGSTRIDE 32  // uint32s between per-WG flags (128B) — separate lines
#define HBYTES (Bdim * Hdim * 2)   // one h buffer in bytes (fragment-major bf16)
#define NBUF   513   // write-once ring: one slot per step -> cached reads never stale
#define PSTRIDE 31   // slot permutation stride (coprime with 513; defeats prefetch)

typedef __attribute__((ext_vector_type(8))) short short8_t;  // 8 bf16 (4 VGPRs)
typedef __attribute__((ext_vector_type(4))) float f32x4;     // MFMA C/D
typedef __attribute__((ext_vector_type(4))) unsigned int u32x4;

__device__ __forceinline__ short f2bf(float x) {
  uint32_t u = __builtin_bit_cast(uint32_t, x);
  u += 0x7fffu + ((u >> 16) & 1u);   // RNE
  return (short)(u >> 16);
}

__device__ __forceinline__ short8_t load8_bf(const float* __restrict__ p) {
  short8_t r;
#pragma unroll
  for (int j = 0; j < 8; ++j) r[j] = f2bf(p[j]);
  return r;
}

// ---- flag barrier helpers ----
// publish: vmcnt(0) drains this wave's h-stores (inline-asm ones the compiler
// doesn't track), __syncthreads joins all waves (so the flag means ALL of this
// WG's h stores are LLC-visible), then one thread stores the arrival flag.
__device__ __forceinline__ void publish(uint32_t* flags, int wg, int tid, uint32_t n) {
  asm volatile("s_waitcnt vmcnt(0)" ::: "memory");
  __syncthreads();
  if (tid == 0)
    __hip_atomic_store(flags + wg * FLAGSTRIDE, n, __ATOMIC_RELAXED, __HIP_MEMORY_SCOPE_AGENT);
}

// wait_quarter (R17: 2-deep pipelined poll, no s_sleep): wave w consumes h cols
// [512w, 512w+512) from WGs [32w, 32w+32). All 64 lanes poll (lane&31)'s flag
// (2 lanes per flag — R12 proved per-line reader count is immaterial). Two
// loads stay in flight; we test the OLDER sample while the newer flies ->
// detect granularity ~ half a round trip, no sleep quantization. Exit when the
// older sample shows every producer >= n — same guarantee as before. The
// trailing in-flight load is drained by the vmcnt(0) that follows the wait.
// RULE (R8): every load issued after this wait depends ONLY on those producers.
__device__ __forceinline__ void wait_quarter(const uint32_t* flags, int wave, int lane, uint32_t n) {
  const uint32_t* f = flags + (wave * 32 + (lane & 31)) * FLAGSTRIDE;
  uint32_t a = __hip_atomic_load(f, __ATOMIC_RELAXED, __HIP_MEMORY_SCOPE_AGENT);
  uint32_t b = __hip_atomic_load(f, __ATOMIC_RELAXED, __HIP_MEMORY_SCOPE_AGENT);
  while (!__all((int)(a >= n))) {
    a = b;
    b = __hip_atomic_load(f, __ATOMIC_RELAXED, __HIP_MEMORY_SCOPE_AGENT);
  }
  __builtin_amdgcn_sched_barrier(0);
}

// ---- h buffer layout (R3): MFMA-fragment-major ----
// 16B block (gc*4 + quad)*16 + batch holds cols [gc*32+quad*8, +8) of one batch.
// Byte offset of (b, col): (col>>3)*256 + b*16 + (col&7)*2.
// Producer stores sc0 sc1 (straight to LLC, the coherence point).
__device__ __forceinline__ void publish_h(char* dstbase, int eb, int ekc, int ecol, float h_own) {
  uint32_t mybits = (uint32_t)(uint16_t)f2bf(h_own);
  uint32_t n1 = (uint32_t)__shfl_xor((int)mybits, 1, 64);
  uint32_t a  = (mybits & 0xffffu) | (n1 << 16);            // cols j, j+1
  uint32_t b  = (uint32_t)__shfl_xor((int)a, 2, 64);        // cols j+2, j+3
  uint32_t c4 = (uint32_t)__shfl_xor((int)a, 4, 64);        // cols j+4, j+5
  uint32_t d  = (uint32_t)__shfl_xor((int)b, 4, 64);        // cols j+6, j+7
  if ((ekc & 7) == 0) {
    u32x4 q; q.x = a; q.y = b; q.z = c4; q.w = d;
    char* dst = dstbase + ((size_t)(ecol >> 3) * 256 + (size_t)eb * 16);
    asm volatile("global_store_dwordx4 %0, %1, off sc0 sc1" :: "v"(dst), "v"(q) : "memory");
  }
}

// Shared per-thread setup packed into a macro to keep the two kernels in sync.
#define KERNEL_PROLOGUE                                                          \
  const int tid  = threadIdx.x;                                                  \
  const int wg   = blockIdx.x;                                                   \
  const int wave = tid >> 6;                                                     \
  const int lane = tid & 63;                                                     \
  const int ln16 = lane & 15;                                                    \
  const int quad = lane >> 4;                                                    \
  const int colbase = wg * KC;                                                   \
  const int kwave   = wave * (Hdim / 4);                                         \
  __shared__ float s_red[4][3][16][16];                                          \
  __shared__ float s_x3[4][16];                                                  \
  short8_t wf0[NCHUNK], wf1[NCHUNK], wf2[NCHUNK], wt[NCHUNK];                    \
  _Pragma("unroll")                                                              \
  for (int c = 0; c < NCHUNK; ++c) {                                             \
    const int k0 = kwave + c * 32 + quad * 8;                                    \
    wf0[c] = load8_bf(w_hh + (size_t)(0 * Hdim + colbase + ln16) * Hdim + k0);   \
    wf1[c] = load8_bf(w_hh + (size_t)(1 * Hdim + colbase + ln16) * Hdim + k0);   \
    wf2[c] = load8_bf(w_hh + (size_t)(2 * Hdim + colbase + ln16) * Hdim + k0);   \
    short8_t g = {0, 0, 0, 0, 0, 0, 0, 0};                                       \
    if (ln16 == 0) g = load8_bf(w_traj + k0);                                    \
    wt[c] = g;                                                                   \
  }                                                                              \
  const int eb   = tid >> 4;                                                     \
  const int ekc  = tid & 15;                                                     \
  const int ecol = colbase + ekc;                                                \
  const float wr = w_ih[ecol], wz = w_ih[Hdim + ecol], wn = w_ih[2 * Hdim + ecol];\
  const float br = b_ih[ecol] + b_hh[ecol];                                      \
  const float bz = b_ih[Hdim + ecol] + b_hh[Hdim + ecol];                        \
  const float bin = b_ih[2 * Hdim + ecol];                                       \
  const float bhn = b_hh[2 * Hdim + ecol];                                       \
  const float bt  = b_traj[0];                                                   \
  float h_own = traj_z[eb * Hdim + ecol];                                        \
  float x_reg = traj_input[eb * Tsteps];

#define MFMA_GROUP(G, VM)                                                      \
    asm volatile("s_waitcnt vmcnt(" #VM ")" ::: "memory");                     \
    __builtin_amdgcn_sched_barrier(0);                                         \
    _Pragma("unroll")                                                          \
    for (int c = (G) * 4; c < (G) * 4 + 4; ++c) {                              \
      a0 = __builtin_amdgcn_mfma_f32_16x16x32_bf16(af[c], wf0[c], a0, 0, 0, 0);\
      a1 = __builtin_amdgcn_mfma_f32_16x16x32_bf16(af[c], wf1[c], a1, 0, 0, 0);\
      a2 = __builtin_amdgcn_mfma_f32_16x16x32_bf16(af[c], wf2[c], a2, 0, 0, 0);\
      a3 = __builtin_amdgcn_mfma_f32_16x16x32_bf16(af[c], wt[c],  a3, 0, 0, 0);\
    }

#define KERNEL_TAIL                                                              \
    _Pragma("unroll")                                                            \
    for (int r = 0; r < 4; ++r) {                                                \
      const int m = quad * 4 + r;                                                \
      s_red[wave][0][m][ln16] = a0[r];                                           \
      s_red[wave][1][m][ln16] = a1[r];                                           \
      s_red[wave][2][m][ln16] = a2[r];                                           \
    }                                                                            \
    if (ln16 == 0) {                                                             \
      _Pragma("unroll")                                                          \
      for (int r = 0; r < 4; ++r) s_x3[wave][quad * 4 + r] = a3[r];              \
    }                                                                            \
    __syncthreads();                                                             \
    if (i > 0) {                                                                 \
      const float xd = ((s_x3[0][eb] + s_x3[1][eb]) + s_x3[2][eb]) + s_x3[3][eb];\
      x_reg += xd + bt;                                                          \
    }                                                                            \
    if (i == Tsteps) {                                                           \
      if (wg == 0 && ekc == 0) out[eb * Tsteps + (i - 1)] = x_reg;               \
      break;                                                                     \
    }                                                                            \
    const float gr = ((s_red[0][0][eb][ekc] + s_red[1][0][eb][ekc]) + s_red[2][0][eb][ekc]) + s_red[3][0][eb][ekc]; \
    const float gz = ((s_red[0][1][eb][ekc] + s_red[1][1][eb][ekc]) + s_red[2][1][eb][ekc]) + s_red[3][1][eb][ekc]; \
    const float gn = ((s_red[0][2][eb][ekc] + s_red[1][2][eb][ekc]) + s_red[2][2][eb][ekc]) + s_red[3][2][eb][ekc]; \
    const float x  = x_reg;                                                      \
    const float rr = 1.f / (1.f + expf(-(x * wr + br + gr)));                    \
    const float zz = 1.f / (1.f + expf(-(x * wz + bz + gz)));                    \
    const float nn = tanhf(x * wn + bin + rr * (gn + bhn));                      \
    h_own = (1.f - zz) * nn + zz * h_own;

// ================= RING kernel: write-once slots, CACHED consumer reads ======
// Slot perm(i) = (i*31) % 513 holds h_i. Lines of each slot are COLD until the
// producer's single sc0sc1 write -> a cached read can never hit stale data; the
// L2 miss fetches the post-write line from LLC. (R16: verified correct, +5%.)
__global__ void __launch_bounds__(TPB, 1) traj_kernel_ring(
    const float* __restrict__ traj_z, const float* __restrict__ traj_input,
    const float* __restrict__ w_ih, const float* __restrict__ b_ih,
    const float* __restrict__ w_hh, const float* __restrict__ b_hh,
    const float* __restrict__ w_traj, const float* __restrict__ b_traj,
    float* __restrict__ out, char* __restrict__ ring, uint32_t* __restrict__ flags)
{
  KERNEL_PROLOGUE

  publish_h(ring /*slot 0*/, eb, ekc, ecol, h_own);
  publish(flags, wg, tid, 1);

  int rd = 0;   // perm(i): current read slot
  for (int i = 0; i <= Tsteps; ++i) {
    wait_quarter(flags, wave, lane, (uint32_t)(i + 1));
    asm volatile("s_waitcnt vmcnt(0)" ::: "memory");  // drains poll tail; vmcnt exact

    // CACHED coalesced loads of h_i; counted-vmcnt overlap as R6.
    const char* hbase = ring + (size_t)rd * HBYTES
                      + (size_t)(kwave >> 5) * 1024 + (size_t)lane * 16;
    short8_t af[NCHUNK];
#pragma unroll
    for (int c = 0; c < NCHUNK; ++c) {
      asm volatile("global_load_dwordx4 %0, %1, off"
                   : "=v"(af[c]) : "v"(hbase + (size_t)c * 1024));
    }

    f32x4 a0 = {0.f, 0.f, 0.f, 0.f}, a1 = a0, a2 = a0, a3 = a0;
    MFMA_GROUP(0, 12)
    MFMA_GROUP(1, 8)
    MFMA_GROUP(2, 4)
    MFMA_GROUP(3, 0)

    KERNEL_TAIL

    int wr_slot = rd + PSTRIDE; if (wr_slot >= NBUF) wr_slot -= NBUF;  // perm(i+1)
    publish_h(ring + (size_t)wr_slot * HBYTES, eb, ekc, ecol, h_own);
    publish(flags, wg, tid, (uint32_t)(i + 2));
    if (wg == 0 && i > 0 && ekc == 0) out[eb * Tsteps + (i - 1)] = x_reg;
    rd = wr_slot;
  }
}

// ================= BASE kernel: 2-buffer uncached protocol (fallback) ========
__global__ void __launch_bounds__(TPB, 1) traj_kernel_base(
    const float* __restrict__ traj_z, const float* __restrict__ traj_input,
    const float* __restrict__ w_ih, const float* __restrict__ b_ih,
    const float* __restrict__ w_hh, const float* __restrict__ b_hh,
    const float* __restrict__ w_traj, const float* __restrict__ b_traj,
    float* __restrict__ out, char* __restrict__ hbuf, uint32_t* __restrict__ flags)
{
  KERNEL_PROLOGUE

  publish_h(hbuf /*parity 0*/, eb, ekc, ecol, h_own);
  publish(flags, wg, tid, 1);

  for (int i = 0; i <= Tsteps; ++i) {
    wait_quarter(flags, wave, lane, (uint32_t)(i + 1));
    asm volatile("s_waitcnt vmcnt(0)" ::: "memory");

    const char* hbase = hbuf + (size_t)(i & 1) * HBYTES
                      + (size_t)(kwave >> 5) * 1024 + (size_t)lane * 16;
    short8_t af[NCHUNK];
#pragma unroll
    for (int c = 0; c < NCHUNK; ++c) {
      asm volatile("global_load_dwordx4 %0, %1, off sc0 sc1"
                   : "=v"(af[c]) : "v"(hbase + (size_t)c * 1024));
    }

    f32x4 a0 = {0.f, 0.f, 0.f, 0.f}, a1 = a0, a2 = a0, a3 = a0;
    MFMA_GROUP(0, 12)
    MFMA_GROUP(1, 8)
    MFMA_GROUP(2, 4)
    MFMA_GROUP(3, 0)

    KERNEL_TAIL

    publish_h(hbuf + (size_t)((i + 1) & 1) * HBYTES, eb, ekc, ecol, h_own);
    publish(flags, wg, tid, (uint32_t)(i + 2));
    if (wg == 0 && i > 0 && ekc == 0) out[eb * Tsteps + (i - 1)] = x_reg;
  }
}

extern "C" void kernel_launch(void* const* d_in, const int* in_sizes, int n_in,
                              void* d_out, int out_size, void* d_ws, size_t ws_size,
                              hipStream_t stream) {
  const float* traj_z     = (const float*)d_in[0];
  const float* traj_input = (const float*)d_in[1];
  const float* w_ih   = (const float*)d_in[2];
  const float* b_ih   = (const float*)d_in[3];
  const float* w_hh   = (const float*)d_in[4];
  const float* b_hh   = (const float*)d_in[5];
  const float* w_traj = (const float*)d_in[6];
  const float* b_traj = (const float*)d_in[7];
  float* out = (float*)d_out;

  uint8_t*  ws    = (uint8_t*)d_ws;
  uint32_t* flags = (uint32_t*)ws;                 // NWG*FLAGSTRIDE u32 = 16 KB
  char*     hbuf  = (char*)(ws + 16384);

  (void)hipMemsetAsync(flags, 0, NWG * FLAGSTRIDE * 4, stream);

  const size_t ring_need = 16384ull + (size_t)NBUF * HBYTES;  // ~33.7 MB
  if (ws_size >= ring_need) {
    hipLaunchKernelGGL(traj_kernel_ring, dim3(NWG), dim3(TPB), 0, stream,
                       traj_z, traj_input, w_ih, b_ih, w_hh, b_hh, w_traj, b_traj,
                       out, hbuf, flags);
  } else {
    hipLaunchKernelGGL(traj_kernel_base, dim3(NWG), dim3(TPB), 0, stream,
                       traj_z, traj_input, w_ih, b_ih, w_hh, b_hh, w_traj, b_traj,
                       out, hbuf, flags);
  }
}